// Round 20
// baseline (364.154 us; speedup 1.0000x reference)
//
#include <hip/hip_runtime.h>
#include <hip/hip_bf16.h>

// RoutingCapsules on MI355X (gfx950)
// x: [B=32, Nin=2048, Din=16] f32
// W: [1, Nin=2048, Nout=64, Dout=32, Din=16] f32
// out v: [B=32, Nout=64, Dout=32] f32
//
// Round-20 = round-19 with the compile fix: __builtin_nontemporal_store needs
// a clang native vector type, not HIP's float4 class. Use ext_vector_type(4).
// Config: NT u-store (r18 proved net win: +14us pass1u, -26us downstream L2
// writeback relief) + cvt_pk pack + pass23u 1-deep prefetch + NT part2 store.

#define B_   32
#define NIN  2048
#define DIN  16
#define NOUT 64
#define DOUT 32
// pass1 / fallback (r8 structure)
#define BQ   8
#define NCHB 16
#define CG   (NIN / NCHB)               // 128
#define NBLK (CG * (B_ / BQ))           // 512
#define TPB  1024
#define PART_PER_BLK (BQ * NOUT * DOUT / 2)   // 8192 float2 (64 KB)
// pass2/3 u-reader
#define NC2   16                        // n per block
#define NCHK2 (NIN / NC2)               // 128 chunks
#define NBLK2 ((B_ / 8) * NCHK2)        // 512 blocks
#define TPB2  512

typedef float f4v __attribute__((ext_vector_type(4)));   // NT-store-compatible

__device__ __forceinline__ unsigned pack_bf16(float a, float b) {
    // paired HW convert: compiler folds to v_cvt_pk_bf16_f32 (RNE)
    const unsigned lo = __bfloat16_as_ushort(__float2bfloat16(a));
    const unsigned hi = __bfloat16_as_ushort(__float2bfloat16(b));
    return lo | (hi << 16);
}

// ---- pass1: W-sweep (uniform c) + fused u-bf16 NT store (r17 config) ----
__global__ __launch_bounds__(TPB)
void caps_pass1u(const float* __restrict__ W, const float* __restrict__ x,
                 unsigned* __restrict__ uws, float2* __restrict__ part)
{
    const int t  = threadIdx.x;       // 0..1023
    const int o  = t >> 4;            // 0..63
    const int dg = t & 15;            // 0..15
    const int d0 = dg << 1;           // 0,2,..,30

    const int bid  = blockIdx.x;
    const int xcd  = bid & 7;
    const int j    = bid >> 3;
    const int cg   = xcd * (CG / 8) + (j >> 2);
    const int quad = j & 3;
    const int nbase = cg * NCHB;
    const int bbase = quad * BQ;

    __shared__ float4 xs[BQ][NCHB * DIN / 4];   // 8 KB

    if (t < BQ * NCHB * DIN / 4) {
        const int bb = t >> 6;
        const int k  = t & 63;
        xs[bb][k] = ((const float4*)x)[(size_t)(bbase + bb) * (NIN * DIN / 4)
                                       + (size_t)nbase * (DIN / 4) + k];
    }

    float acc0[BQ], acc1[BQ];
#pragma unroll
    for (int bb = 0; bb < BQ; ++bb) { acc0[bb] = 0.f; acc1[bb] = 0.f; }

    __syncthreads();

    for (int nn = 0; nn < NCHB; ++nn) {
        const int n = nbase + nn;
        const float4* wp = (const float4*)(W +
            (((size_t)n * NOUT + o) * DOUT + d0) * DIN);
        float4 w[8];
#pragma unroll
        for (int q = 0; q < 8; ++q) w[q] = wp[q];
#pragma unroll
        for (int bb = 0; bb < BQ; ++bb) {
            const float4* xr = &xs[bb][nn * 4];
            float u0 = 0.f, u1 = 0.f;
#pragma unroll
            for (int q = 0; q < 4; ++q) {
                const float4 xv = xr[q];
                u0 += w[q].x*xv.x + w[q].y*xv.y + w[q].z*xv.z + w[q].w*xv.w;
                u1 += w[4+q].x*xv.x + w[4+q].y*xv.y + w[4+q].z*xv.z + w[4+q].w*xv.w;
            }
            acc0[bb] += u0;
            acc1[bb] += u1;
            // NT store: keeps L2 clean of the 256MiB u stream -> downstream
            // pass23u's u reads don't compete with dirty writebacks (r18 proof)
            __builtin_nontemporal_store(pack_bf16(u0, u1),
                &uws[((size_t)(bbase + bb) * NIN + n) * 1024 + t]);
        }
    }

#pragma unroll
    for (int bb = 0; bb < BQ; ++bb) {
        float2* base = part + (size_t)(cg * 4 + quad) * PART_PER_BLK;
        base[bb * (NOUT * DOUT / 2) + o * (DOUT / 2) + dg] =
            make_float2(acc0[bb] * (1.0f / 64.0f), acc1[bb] * (1.0f / 64.0f));
    }
}

// ---- pass2/3: lane = o, wave = b; thread-local; 1-deep prefetch pipeline ----
#define LOGIT_PAIR(u32, k)                                             \
    {   const float uE = __uint_as_float((u32) << 16);                 \
        const float uO = __uint_as_float((u32) & 0xffff0000u);         \
        logit += uE * vr[2*(k)] + uO * vr[2*(k)+1]; }

#define ACC_PAIR(u32, k)                                               \
    {   const float uE = __uint_as_float((u32) << 16);                 \
        const float uO = __uint_as_float((u32) & 0xffff0000u);         \
        acc[2*(k)]   += c * uE;                                        \
        acc[2*(k)+1] += c * uO; }

__global__ __launch_bounds__(TPB2)
void caps_pass23u(const unsigned* __restrict__ uws, const float* __restrict__ v_in,
                  float* __restrict__ part2)
{
    const int t    = threadIdx.x;     // 0..511
    const int o    = t & 63;          // lane = capsule-out
    const int wid  = t >> 6;          // wave -> batch offset

    const int bid   = blockIdx.x;
    const int b     = (bid >> 7) * 8 + wid;   // 4 b-groups x 8 waves
    const int chunk = bid & 127;              // 0..127
    const int nbase = chunk * NC2;

    // v[b][o][0..31]: 8 float4 = 32 regs, thread-local
    float vr[DOUT];
    {
        const float4* vp = (const float4*)(v_in + ((size_t)b * NOUT + o) * DOUT);
#pragma unroll
        for (int q = 0; q < 8; ++q) {
            const float4 vv = vp[q];
            vr[q*4+0] = vv.x; vr[q*4+1] = vv.y; vr[q*4+2] = vv.z; vr[q*4+3] = vv.w;
        }
    }

    float acc[DOUT];
#pragma unroll
    for (int d = 0; d < DOUT; ++d) acc[d] = 0.f;

    // u row for (b, n): 1024 uints = 256 uint4; this o starts at uint4 index o*4
    const uint4* ub = (const uint4*)(uws + ((size_t)b * NIN + nbase) * 1024) + o * 4;

    // prologue: load nn=0
    uint4 c0 = ub[0], c1 = ub[1], c2 = ub[2], c3 = ub[3];

#pragma unroll 1
    for (int nn = 0; nn < NC2; ++nn) {
        // issue next tile's loads before computing current (hide L3/HBM latency)
        uint4 n0 = c0, n1 = c1, n2 = c2, n3 = c3;
        if (nn + 1 < NC2) {
            const uint4* un = ub + (size_t)(nn + 1) * 256;
            n0 = un[0]; n1 = un[1]; n2 = un[2]; n3 = un[3];
        }

        float logit = 0.f;
        LOGIT_PAIR(c0.x, 0)  LOGIT_PAIR(c0.y, 1)  LOGIT_PAIR(c0.z, 2)  LOGIT_PAIR(c0.w, 3)
        LOGIT_PAIR(c1.x, 4)  LOGIT_PAIR(c1.y, 5)  LOGIT_PAIR(c1.z, 6)  LOGIT_PAIR(c1.w, 7)
        LOGIT_PAIR(c2.x, 8)  LOGIT_PAIR(c2.y, 9)  LOGIT_PAIR(c2.z,10)  LOGIT_PAIR(c2.w,11)
        LOGIT_PAIR(c3.x,12)  LOGIT_PAIR(c3.y,13)  LOGIT_PAIR(c3.z,14)  LOGIT_PAIR(c3.w,15)

        // in-wave softmax over o = 64 lanes; lane IS o -> no broadcast needed
        const float e = __expf(logit);         // |logit| << 88, no max-sub
        float sm = e;
#pragma unroll
        for (int m = 1; m < 64; m <<= 1) sm += __shfl_xor(sm, m);
        const float c = e / sm;

        ACC_PAIR(c0.x, 0)  ACC_PAIR(c0.y, 1)  ACC_PAIR(c0.z, 2)  ACC_PAIR(c0.w, 3)
        ACC_PAIR(c1.x, 4)  ACC_PAIR(c1.y, 5)  ACC_PAIR(c1.z, 6)  ACC_PAIR(c1.w, 7)
        ACC_PAIR(c2.x, 8)  ACC_PAIR(c2.y, 9)  ACC_PAIR(c2.z,10)  ACC_PAIR(c2.w,11)
        ACC_PAIR(c3.x,12)  ACC_PAIR(c3.y,13)  ACC_PAIR(c3.z,14)  ACC_PAIR(c3.w,15)

        c0 = n0; c1 = n1; c2 = n2; c3 = n3;
    }

    // part2[b][chunk][o][d]: 128B per thread; NT (consumed once, cross-XCD)
    float* pb = part2 + (((size_t)b * NCHK2 + chunk) * NOUT + o) * DOUT;
#pragma unroll
    for (int d = 0; d < DOUT; d += 4) {
        f4v val = { acc[d], acc[d+1], acc[d+2], acc[d+3] };
        __builtin_nontemporal_store(val, (f4v*)(pb + d));
    }
}

// sum 128 chunk-partials per element, then squash per (b,o) row
__global__ __launch_bounds__(256)
void reduce_squash2(const float* __restrict__ part2, float* __restrict__ vout,
                    int accumulate)
{
    const int id = blockIdx.x * 256 + threadIdx.x;   // 0..65535 = b*2048+o*32+d
    const float* p = part2 + (size_t)(id >> 11) * (NCHK2 * NOUT * DOUT) + (id & 2047);
    float s = 0.f;
#pragma unroll 8
    for (int ch = 0; ch < NCHK2; ++ch) s += p[(size_t)ch * (NOUT * DOUT)];

    float sq = s * s;
#pragma unroll
    for (int m = 1; m < 32; m <<= 1) sq += __shfl_xor(sq, m);  // row = 32 lanes
    const float f = sq / ((1.0f + sq) * sqrtf(sq + 1e-8f));
    const float v = s * f;
    if (accumulate) vout[id] += v;
    else            vout[id] = v;
}

// ---------- r8 kernel (fallback partial path + atomic fallback) ----------
template<int PASS, bool ATOMIC>
__global__ __launch_bounds__(TPB)
void caps_pass(const float* __restrict__ W, const float* __restrict__ x,
               const float* __restrict__ v_in, float* __restrict__ s_out,
               float2* __restrict__ part)
{
    const int t    = threadIdx.x;
    const int o    = t >> 4;
    const int dg   = t & 15;
    const int d0   = dg << 1;
    const int lane = t & 63;
    const int wid  = t >> 6;

    const int bid  = blockIdx.x;
    const int xcd  = bid & 7;
    const int j    = bid >> 3;
    const int cg   = xcd * (CG / 8) + (j >> 2);
    const int quad = j & 3;
    const int nbase = cg * NCHB;
    const int bbase = quad * BQ;

    __shared__ float4 xs[BQ][NCHB * DIN / 4];

    if (t < BQ * NCHB * DIN / 4) {
        const int bb = t >> 6;
        const int k  = t & 63;
        xs[bb][k] = ((const float4*)x)[(size_t)(bbase + bb) * (NIN * DIN / 4)
                                       + (size_t)nbase * (DIN / 4) + k];
    }

    float acc0[BQ], acc1[BQ];
#pragma unroll
    for (int bb = 0; bb < BQ; ++bb) { acc0[bb] = 0.f; acc1[bb] = 0.f; }

    __syncthreads();

    if constexpr (PASS == 1) {
        for (int nn = 0; nn < NCHB; ++nn) {
            const float4* wp = (const float4*)(W +
                (((size_t)(nbase + nn) * NOUT + o) * DOUT + d0) * DIN);
            float4 w[8];
#pragma unroll
            for (int q = 0; q < 8; ++q) w[q] = wp[q];
#pragma unroll
            for (int bb = 0; bb < BQ; ++bb) {
                const float4* xr = &xs[bb][nn * 4];
                float u0 = 0.f, u1 = 0.f;
#pragma unroll
                for (int q = 0; q < 4; ++q) {
                    const float4 xv = xr[q];
                    u0 += w[q].x*xv.x + w[q].y*xv.y + w[q].z*xv.z + w[q].w*xv.w;
                    u1 += w[4+q].x*xv.x + w[4+q].y*xv.y + w[4+q].z*xv.z + w[4+q].w*xv.w;
                }
                acc0[bb] += u0;
                acc1[bb] += u1;
            }
        }
    } else {
        __shared__ float  lg[BQ * NOUT];
        __shared__ float  cs[BQ * NOUT];
        __shared__ float2 ustash[BQ][TPB];
        for (int nn = 0; nn < NCHB; ++nn) {
            const float4* wp = (const float4*)(W +
                (((size_t)(nbase + nn) * NOUT + o) * DOUT + d0) * DIN);
            float4 w[8];
#pragma unroll
            for (int q = 0; q < 8; ++q) w[q] = wp[q];
#pragma unroll
            for (int bb = 0; bb < BQ; ++bb) {
                const float4* xr = &xs[bb][nn * 4];
                float u0 = 0.f, u1 = 0.f;
#pragma unroll
                for (int q = 0; q < 4; ++q) {
                    const float4 xv = xr[q];
                    u0 += w[q].x*xv.x + w[q].y*xv.y + w[q].z*xv.z + w[q].w*xv.w;
                    u1 += w[4+q].x*xv.x + w[4+q].y*xv.y + w[4+q].z*xv.z + w[4+q].w*xv.w;
                }
                const float2 vvv = ((const float2*)v_in)[
                    (size_t)(bbase + bb) * (NOUT * DOUT / 2) + o * (DOUT / 2) + dg];
                float p = u0 * vvv.x + u1 * vvv.y;
                p += __shfl_xor(p, 1);
                p += __shfl_xor(p, 2);
                p += __shfl_xor(p, 4);
                p += __shfl_xor(p, 8);
                if (dg == 0) lg[bb * NOUT + o] = p;
                ustash[bb][t] = make_float2(u0, u1);
            }
            __syncthreads();
            if (wid < BQ) {
                const float e = __expf(lg[wid * NOUT + lane]);
                float sm = e;
#pragma unroll
                for (int m = 1; m < 64; m <<= 1) sm += __shfl_xor(sm, m);
                cs[wid * NOUT + lane] = e / sm;
            }
            __syncthreads();
#pragma unroll
            for (int bb = 0; bb < BQ; ++bb) {
                const float c = cs[bb * NOUT + o];
                const float2 u = ustash[bb][t];
                acc0[bb] += c * u.x;
                acc1[bb] += c * u.y;
            }
        }
    }

    const float scale = (PASS == 1) ? (1.0f / 64.0f) : 1.0f;
    if constexpr (ATOMIC) {
#pragma unroll
        for (int bb = 0; bb < BQ; ++bb) {
            float* dst = &s_out[((size_t)(bbase + bb) * NOUT + o) * DOUT + d0];
            atomicAdd(dst,     acc0[bb] * scale);
            atomicAdd(dst + 1, acc1[bb] * scale);
        }
    } else {
        float2* base = part + (size_t)(cg * 4 + quad) * PART_PER_BLK;
#pragma unroll
        for (int bb = 0; bb < BQ; ++bb)
            base[bb * (NOUT * DOUT / 2) + o * (DOUT / 2) + dg] =
                make_float2(acc0[bb] * scale, acc1[bb] * scale);
    }
}

// r8 reduce: sum 128 chunk-partials, squash per (b,o) row (16-lane groups)
__global__ __launch_bounds__(256)
void reduce_squash(const float2* __restrict__ part, float* __restrict__ vout,
                   int accumulate)
{
    const int id = blockIdx.x * 256 + threadIdx.x;
    const int dg = id & 15;
    const int o  = (id >> 4) & 63;
    const int b  = id >> 10;
    const int quad = b >> 3, bb = b & 7;
    const size_t base = (size_t)bb * (NOUT * DOUT / 2) + o * (DOUT / 2) + dg;

    float2 a0 = make_float2(0.f, 0.f), a1 = make_float2(0.f, 0.f);
    for (int cg = 0; cg < CG; cg += 2) {
        const float2 p0 = part[(size_t)(cg * 4 + quad) * PART_PER_BLK + base];
        const float2 p1 = part[(size_t)((cg + 1) * 4 + quad) * PART_PER_BLK + base];
        a0.x += p0.x; a0.y += p0.y;
        a1.x += p1.x; a1.y += p1.y;
    }
    const float sx = a0.x + a1.x, sy = a0.y + a1.y;

    float sq = sx * sx + sy * sy;
    sq += __shfl_xor(sq, 1);
    sq += __shfl_xor(sq, 2);
    sq += __shfl_xor(sq, 4);
    sq += __shfl_xor(sq, 8);
    const float f = sq / ((1.0f + sq) * sqrtf(sq + 1e-8f));

    float2* vo = (float2*)vout;
    float2 r = make_float2(sx * f, sy * f);
    if (accumulate) {
        const float2 old = vo[id];
        r.x += old.x; r.y += old.y;
    }
    vo[id] = r;
}

__global__ void squash_k(const float* __restrict__ s, float* __restrict__ vout,
                         int accumulate)
{
    const int idx = blockIdx.x * 256 + threadIdx.x;
    const float val = s[idx];
    float sq = val * val;
#pragma unroll
    for (int m = 1; m < 32; m <<= 1) sq += __shfl_xor(sq, m);
    const float f = sq / ((1.0f + sq) * sqrtf(sq + 1e-8f));
    const float v = val * f;
    if (accumulate) vout[idx] += v;
    else            vout[idx] = v;
}

extern "C" void kernel_launch(void* const* d_in, const int* in_sizes, int n_in,
                              void* d_out, int out_size, void* d_ws, size_t ws_size,
                              hipStream_t stream)
{
    (void)in_sizes; (void)n_in; (void)out_size;
    const float* x = (const float*)d_in[0];
    const float* W = (const float*)d_in[1];
    float* out = (float*)d_out;

    const size_t uBytes    = (size_t)B_ * NIN * NOUT * DOUT * 2;           // 256 MiB
    const size_t partBytes = (size_t)NBLK * PART_PER_BLK * sizeof(float2); // 32 MiB
    const size_t vBytes    = (size_t)B_ * NOUT * DOUT * sizeof(float);     // 256 KiB

    if (ws_size >= uBytes + partBytes + vBytes) {
        // ---- main path: u materialized in bf16 (r14 layout) ----
        unsigned* uws  = (unsigned*)d_ws;
        float2*   p1   = (float2*)((char*)d_ws + uBytes);
        float*    p2   = (float*)p1;                       // 32 MiB, reused
        float*    vA   = (float*)((char*)d_ws + uBytes + partBytes);

        caps_pass1u<<<dim3(NBLK), dim3(TPB), 0, stream>>>(W, x, uws, p1);
        reduce_squash<<<dim3(128), dim3(256), 0, stream>>>(p1, vA, 0);     // vA = v1

        caps_pass23u<<<dim3(NBLK2), dim3(TPB2), 0, stream>>>(uws, vA, p2);
        reduce_squash2<<<dim3(256), dim3(256), 0, stream>>>(p2, vA, 1);    // vA = v1+v2

        caps_pass23u<<<dim3(NBLK2), dim3(TPB2), 0, stream>>>(uws, vA, p2);
        reduce_squash2<<<dim3(256), dim3(256), 0, stream>>>(p2, out, 0);   // out = v3
    } else if (ws_size >= partBytes + vBytes) {
        // ---- r8 partial path ----
        float2* part = (float2*)d_ws;
        float*  vA   = (float*)((char*)d_ws + partBytes);

        caps_pass<1, false><<<dim3(NBLK), dim3(TPB), 0, stream>>>(W, x, nullptr, nullptr, part);
        reduce_squash<<<dim3(128), dim3(256), 0, stream>>>(part, vA, 0);

        caps_pass<2, false><<<dim3(NBLK), dim3(TPB), 0, stream>>>(W, x, vA, nullptr, part);
        reduce_squash<<<dim3(128), dim3(256), 0, stream>>>(part, vA, 1);

        caps_pass<2, false><<<dim3(NBLK), dim3(TPB), 0, stream>>>(W, x, vA, nullptr, part);
        reduce_squash<<<dim3(128), dim3(256), 0, stream>>>(part, out, 0);
    } else {
        // ---- atomic fallback ----
        float* s  = (float*)d_ws;
        float* vA = s + B_ * NOUT * DOUT;

        hipMemsetAsync(s, 0, vBytes, stream);
        caps_pass<1, true><<<dim3(NBLK), dim3(TPB), 0, stream>>>(W, x, nullptr, s, nullptr);
        squash_k<<<dim3(256), dim3(256), 0, stream>>>(s, vA, 0);

        hipMemsetAsync(s, 0, vBytes, stream);
        caps_pass<2, true><<<dim3(NBLK), dim3(TPB), 0, stream>>>(W, x, vA, s, nullptr);
        squash_k<<<dim3(256), dim3(256), 0, stream>>>(s, vA, 1);

        hipMemsetAsync(s, 0, vBytes, stream);
        caps_pass<2, true><<<dim3(NBLK), dim3(TPB), 0, stream>>>(W, x, vA, s, nullptr);
        squash_k<<<dim3(256), dim3(256), 0, stream>>>(s, out, 0);
    }
}

// Round 21
// 335.642 us; speedup vs baseline: 1.0849x; 1.0849x over previous
//
#include <hip/hip_runtime.h>
#include <hip/hip_bf16.h>

// RoutingCapsules on MI355X (gfx950)
// x: [B=32, Nin=2048, Din=16] f32
// W: [1, Nin=2048, Nout=64, Dout=32, Din=16] f32
// out v: [B=32, Nout=64, Dout=32] f32
//
// Round-21 = r17 config exactly (measured best, 336us):
//   - pass1u: W-sweep + fused bf16-u materialization, NT u-store (u is 256MiB,
//     next reader can't L2-hit anyway -> NT keeps L2 clean; r18/r20 proven)
//   - part2: REGULAR store (read within us by reduce_squash2 -> must stay
//     in L2; r20 proved NT here costs +28us)
//   - pass23u: lane=o wave=b thread-local softmax, 1-deep prefetch
// pass23u streams u at ~5.3 TB/s (~85% of achievable) -> at roofline.
// pass1u is HBM-write-stream bound; 4 micro-knobs each moved <=15us.

#define B_   32
#define NIN  2048
#define DIN  16
#define NOUT 64
#define DOUT 32
// pass1 / fallback (r8 structure)
#define BQ   8
#define NCHB 16
#define CG   (NIN / NCHB)               // 128
#define NBLK (CG * (B_ / BQ))           // 512
#define TPB  1024
#define PART_PER_BLK (BQ * NOUT * DOUT / 2)   // 8192 float2 (64 KB)
// pass2/3 u-reader
#define NC2   16                        // n per block
#define NCHK2 (NIN / NC2)               // 128 chunks
#define NBLK2 ((B_ / 8) * NCHK2)        // 512 blocks
#define TPB2  512

__device__ __forceinline__ unsigned pack_bf16(float a, float b) {
    // paired HW convert: compiler folds to v_cvt_pk_bf16_f32 (RNE)
    const unsigned lo = __bfloat16_as_ushort(__float2bfloat16(a));
    const unsigned hi = __bfloat16_as_ushort(__float2bfloat16(b));
    return lo | (hi << 16);
}

// ---- pass1: W-sweep (uniform c) + fused u-bf16 NT store ----
__global__ __launch_bounds__(TPB)
void caps_pass1u(const float* __restrict__ W, const float* __restrict__ x,
                 unsigned* __restrict__ uws, float2* __restrict__ part)
{
    const int t  = threadIdx.x;       // 0..1023
    const int o  = t >> 4;            // 0..63
    const int dg = t & 15;            // 0..15
    const int d0 = dg << 1;           // 0,2,..,30

    const int bid  = blockIdx.x;
    const int xcd  = bid & 7;
    const int j    = bid >> 3;
    const int cg   = xcd * (CG / 8) + (j >> 2);
    const int quad = j & 3;
    const int nbase = cg * NCHB;
    const int bbase = quad * BQ;

    __shared__ float4 xs[BQ][NCHB * DIN / 4];   // 8 KB

    if (t < BQ * NCHB * DIN / 4) {
        const int bb = t >> 6;
        const int k  = t & 63;
        xs[bb][k] = ((const float4*)x)[(size_t)(bbase + bb) * (NIN * DIN / 4)
                                       + (size_t)nbase * (DIN / 4) + k];
    }

    float acc0[BQ], acc1[BQ];
#pragma unroll
    for (int bb = 0; bb < BQ; ++bb) { acc0[bb] = 0.f; acc1[bb] = 0.f; }

    __syncthreads();

    for (int nn = 0; nn < NCHB; ++nn) {
        const int n = nbase + nn;
        const float4* wp = (const float4*)(W +
            (((size_t)n * NOUT + o) * DOUT + d0) * DIN);
        float4 w[8];
#pragma unroll
        for (int q = 0; q < 8; ++q) w[q] = wp[q];
#pragma unroll
        for (int bb = 0; bb < BQ; ++bb) {
            const float4* xr = &xs[bb][nn * 4];
            float u0 = 0.f, u1 = 0.f;
#pragma unroll
            for (int q = 0; q < 4; ++q) {
                const float4 xv = xr[q];
                u0 += w[q].x*xv.x + w[q].y*xv.y + w[q].z*xv.z + w[q].w*xv.w;
                u1 += w[4+q].x*xv.x + w[4+q].y*xv.y + w[4+q].z*xv.z + w[4+q].w*xv.w;
            }
            acc0[bb] += u0;
            acc1[bb] += u1;
            // NT store: u's next reader can't L2-hit anyway (256MiB, cross-XCD)
            __builtin_nontemporal_store(pack_bf16(u0, u1),
                &uws[((size_t)(bbase + bb) * NIN + n) * 1024 + t]);
        }
    }

#pragma unroll
    for (int bb = 0; bb < BQ; ++bb) {
        float2* base = part + (size_t)(cg * 4 + quad) * PART_PER_BLK;
        base[bb * (NOUT * DOUT / 2) + o * (DOUT / 2) + dg] =
            make_float2(acc0[bb] * (1.0f / 64.0f), acc1[bb] * (1.0f / 64.0f));
    }
}

// ---- pass2/3: lane = o, wave = b; thread-local; 1-deep prefetch pipeline ----
#define LOGIT_PAIR(u32, k)                                             \
    {   const float uE = __uint_as_float((u32) << 16);                 \
        const float uO = __uint_as_float((u32) & 0xffff0000u);         \
        logit += uE * vr[2*(k)] + uO * vr[2*(k)+1]; }

#define ACC_PAIR(u32, k)                                               \
    {   const float uE = __uint_as_float((u32) << 16);                 \
        const float uO = __uint_as_float((u32) & 0xffff0000u);         \
        acc[2*(k)]   += c * uE;                                        \
        acc[2*(k)+1] += c * uO; }

__global__ __launch_bounds__(TPB2)
void caps_pass23u(const unsigned* __restrict__ uws, const float* __restrict__ v_in,
                  float* __restrict__ part2)
{
    const int t    = threadIdx.x;     // 0..511
    const int o    = t & 63;          // lane = capsule-out
    const int wid  = t >> 6;          // wave -> batch offset

    const int bid   = blockIdx.x;
    const int b     = (bid >> 7) * 8 + wid;   // 4 b-groups x 8 waves
    const int chunk = bid & 127;              // 0..127
    const int nbase = chunk * NC2;

    // v[b][o][0..31]: 8 float4 = 32 regs, thread-local
    float vr[DOUT];
    {
        const float4* vp = (const float4*)(v_in + ((size_t)b * NOUT + o) * DOUT);
#pragma unroll
        for (int q = 0; q < 8; ++q) {
            const float4 vv = vp[q];
            vr[q*4+0] = vv.x; vr[q*4+1] = vv.y; vr[q*4+2] = vv.z; vr[q*4+3] = vv.w;
        }
    }

    float acc[DOUT];
#pragma unroll
    for (int d = 0; d < DOUT; ++d) acc[d] = 0.f;

    // u row for (b, n): 1024 uints = 256 uint4; this o starts at uint4 index o*4
    const uint4* ub = (const uint4*)(uws + ((size_t)b * NIN + nbase) * 1024) + o * 4;

    // prologue: load nn=0
    uint4 c0 = ub[0], c1 = ub[1], c2 = ub[2], c3 = ub[3];

#pragma unroll 1
    for (int nn = 0; nn < NC2; ++nn) {
        // issue next tile's loads before computing current (hide L3/HBM latency)
        uint4 n0 = c0, n1 = c1, n2 = c2, n3 = c3;
        if (nn + 1 < NC2) {
            const uint4* un = ub + (size_t)(nn + 1) * 256;
            n0 = un[0]; n1 = un[1]; n2 = un[2]; n3 = un[3];
        }

        float logit = 0.f;
        LOGIT_PAIR(c0.x, 0)  LOGIT_PAIR(c0.y, 1)  LOGIT_PAIR(c0.z, 2)  LOGIT_PAIR(c0.w, 3)
        LOGIT_PAIR(c1.x, 4)  LOGIT_PAIR(c1.y, 5)  LOGIT_PAIR(c1.z, 6)  LOGIT_PAIR(c1.w, 7)
        LOGIT_PAIR(c2.x, 8)  LOGIT_PAIR(c2.y, 9)  LOGIT_PAIR(c2.z,10)  LOGIT_PAIR(c2.w,11)
        LOGIT_PAIR(c3.x,12)  LOGIT_PAIR(c3.y,13)  LOGIT_PAIR(c3.z,14)  LOGIT_PAIR(c3.w,15)

        // in-wave softmax over o = 64 lanes; lane IS o -> no broadcast needed
        const float e = __expf(logit);         // |logit| << 88, no max-sub
        float sm = e;
#pragma unroll
        for (int m = 1; m < 64; m <<= 1) sm += __shfl_xor(sm, m);
        const float c = e / sm;

        ACC_PAIR(c0.x, 0)  ACC_PAIR(c0.y, 1)  ACC_PAIR(c0.z, 2)  ACC_PAIR(c0.w, 3)
        ACC_PAIR(c1.x, 4)  ACC_PAIR(c1.y, 5)  ACC_PAIR(c1.z, 6)  ACC_PAIR(c1.w, 7)
        ACC_PAIR(c2.x, 8)  ACC_PAIR(c2.y, 9)  ACC_PAIR(c2.z,10)  ACC_PAIR(c2.w,11)
        ACC_PAIR(c3.x,12)  ACC_PAIR(c3.y,13)  ACC_PAIR(c3.z,14)  ACC_PAIR(c3.w,15)

        c0 = n0; c1 = n1; c2 = n2; c3 = n3;
    }

    // part2[b][chunk][o][d]: 128B per thread; REGULAR store (read in us by
    // reduce_squash2 -> must stay L2-resident; NT here cost +28us in r20)
    float* pb = part2 + (((size_t)b * NCHK2 + chunk) * NOUT + o) * DOUT;
#pragma unroll
    for (int d = 0; d < DOUT; d += 4)
        *(float4*)(pb + d) = make_float4(acc[d], acc[d+1], acc[d+2], acc[d+3]);
}

// sum 128 chunk-partials per element, then squash per (b,o) row
__global__ __launch_bounds__(256)
void reduce_squash2(const float* __restrict__ part2, float* __restrict__ vout,
                    int accumulate)
{
    const int id = blockIdx.x * 256 + threadIdx.x;   // 0..65535 = b*2048+o*32+d
    const float* p = part2 + (size_t)(id >> 11) * (NCHK2 * NOUT * DOUT) + (id & 2047);
    float s = 0.f;
#pragma unroll 8
    for (int ch = 0; ch < NCHK2; ++ch) s += p[(size_t)ch * (NOUT * DOUT)];

    float sq = s * s;
#pragma unroll
    for (int m = 1; m < 32; m <<= 1) sq += __shfl_xor(sq, m);  // row = 32 lanes
    const float f = sq / ((1.0f + sq) * sqrtf(sq + 1e-8f));
    const float v = s * f;
    if (accumulate) vout[id] += v;
    else            vout[id] = v;
}

// ---------- r8 kernel (fallback partial path + atomic fallback) ----------
template<int PASS, bool ATOMIC>
__global__ __launch_bounds__(TPB)
void caps_pass(const float* __restrict__ W, const float* __restrict__ x,
               const float* __restrict__ v_in, float* __restrict__ s_out,
               float2* __restrict__ part)
{
    const int t    = threadIdx.x;
    const int o    = t >> 4;
    const int dg   = t & 15;
    const int d0   = dg << 1;
    const int lane = t & 63;
    const int wid  = t >> 6;

    const int bid  = blockIdx.x;
    const int xcd  = bid & 7;
    const int j    = bid >> 3;
    const int cg   = xcd * (CG / 8) + (j >> 2);
    const int quad = j & 3;
    const int nbase = cg * NCHB;
    const int bbase = quad * BQ;

    __shared__ float4 xs[BQ][NCHB * DIN / 4];

    if (t < BQ * NCHB * DIN / 4) {
        const int bb = t >> 6;
        const int k  = t & 63;
        xs[bb][k] = ((const float4*)x)[(size_t)(bbase + bb) * (NIN * DIN / 4)
                                       + (size_t)nbase * (DIN / 4) + k];
    }

    float acc0[BQ], acc1[BQ];
#pragma unroll
    for (int bb = 0; bb < BQ; ++bb) { acc0[bb] = 0.f; acc1[bb] = 0.f; }

    __syncthreads();

    if constexpr (PASS == 1) {
        for (int nn = 0; nn < NCHB; ++nn) {
            const float4* wp = (const float4*)(W +
                (((size_t)(nbase + nn) * NOUT + o) * DOUT + d0) * DIN);
            float4 w[8];
#pragma unroll
            for (int q = 0; q < 8; ++q) w[q] = wp[q];
#pragma unroll
            for (int bb = 0; bb < BQ; ++bb) {
                const float4* xr = &xs[bb][nn * 4];
                float u0 = 0.f, u1 = 0.f;
#pragma unroll
                for (int q = 0; q < 4; ++q) {
                    const float4 xv = xr[q];
                    u0 += w[q].x*xv.x + w[q].y*xv.y + w[q].z*xv.z + w[q].w*xv.w;
                    u1 += w[4+q].x*xv.x + w[4+q].y*xv.y + w[4+q].z*xv.z + w[4+q].w*xv.w;
                }
                acc0[bb] += u0;
                acc1[bb] += u1;
            }
        }
    } else {
        __shared__ float  lg[BQ * NOUT];
        __shared__ float  cs[BQ * NOUT];
        __shared__ float2 ustash[BQ][TPB];
        for (int nn = 0; nn < NCHB; ++nn) {
            const float4* wp = (const float4*)(W +
                (((size_t)(nbase + nn) * NOUT + o) * DOUT + d0) * DIN);
            float4 w[8];
#pragma unroll
            for (int q = 0; q < 8; ++q) w[q] = wp[q];
#pragma unroll
            for (int bb = 0; bb < BQ; ++bb) {
                const float4* xr = &xs[bb][nn * 4];
                float u0 = 0.f, u1 = 0.f;
#pragma unroll
                for (int q = 0; q < 4; ++q) {
                    const float4 xv = xr[q];
                    u0 += w[q].x*xv.x + w[q].y*xv.y + w[q].z*xv.z + w[q].w*xv.w;
                    u1 += w[4+q].x*xv.x + w[4+q].y*xv.y + w[4+q].z*xv.z + w[4+q].w*xv.w;
                }
                const float2 vvv = ((const float2*)v_in)[
                    (size_t)(bbase + bb) * (NOUT * DOUT / 2) + o * (DOUT / 2) + dg];
                float p = u0 * vvv.x + u1 * vvv.y;
                p += __shfl_xor(p, 1);
                p += __shfl_xor(p, 2);
                p += __shfl_xor(p, 4);
                p += __shfl_xor(p, 8);
                if (dg == 0) lg[bb * NOUT + o] = p;
                ustash[bb][t] = make_float2(u0, u1);
            }
            __syncthreads();
            if (wid < BQ) {
                const float e = __expf(lg[wid * NOUT + lane]);
                float sm = e;
#pragma unroll
                for (int m = 1; m < 64; m <<= 1) sm += __shfl_xor(sm, m);
                cs[wid * NOUT + lane] = e / sm;
            }
            __syncthreads();
#pragma unroll
            for (int bb = 0; bb < BQ; ++bb) {
                const float c = cs[bb * NOUT + o];
                const float2 u = ustash[bb][t];
                acc0[bb] += c * u.x;
                acc1[bb] += c * u.y;
            }
        }
    }

    const float scale = (PASS == 1) ? (1.0f / 64.0f) : 1.0f;
    if constexpr (ATOMIC) {
#pragma unroll
        for (int bb = 0; bb < BQ; ++bb) {
            float* dst = &s_out[((size_t)(bbase + bb) * NOUT + o) * DOUT + d0];
            atomicAdd(dst,     acc0[bb] * scale);
            atomicAdd(dst + 1, acc1[bb] * scale);
        }
    } else {
        float2* base = part + (size_t)(cg * 4 + quad) * PART_PER_BLK;
#pragma unroll
        for (int bb = 0; bb < BQ; ++bb)
            base[bb * (NOUT * DOUT / 2) + o * (DOUT / 2) + dg] =
                make_float2(acc0[bb] * scale, acc1[bb] * scale);
    }
}

// r8 reduce: sum 128 chunk-partials, squash per (b,o) row (16-lane groups)
__global__ __launch_bounds__(256)
void reduce_squash(const float2* __restrict__ part, float* __restrict__ vout,
                   int accumulate)
{
    const int id = blockIdx.x * 256 + threadIdx.x;
    const int dg = id & 15;
    const int o  = (id >> 4) & 63;
    const int b  = id >> 10;
    const int quad = b >> 3, bb = b & 7;
    const size_t base = (size_t)bb * (NOUT * DOUT / 2) + o * (DOUT / 2) + dg;

    float2 a0 = make_float2(0.f, 0.f), a1 = make_float2(0.f, 0.f);
    for (int cg = 0; cg < CG; cg += 2) {
        const float2 p0 = part[(size_t)(cg * 4 + quad) * PART_PER_BLK + base];
        const float2 p1 = part[(size_t)((cg + 1) * 4 + quad) * PART_PER_BLK + base];
        a0.x += p0.x; a0.y += p0.y;
        a1.x += p1.x; a1.y += p1.y;
    }
    const float sx = a0.x + a1.x, sy = a0.y + a1.y;

    float sq = sx * sx + sy * sy;
    sq += __shfl_xor(sq, 1);
    sq += __shfl_xor(sq, 2);
    sq += __shfl_xor(sq, 4);
    sq += __shfl_xor(sq, 8);
    const float f = sq / ((1.0f + sq) * sqrtf(sq + 1e-8f));

    float2* vo = (float2*)vout;
    float2 r = make_float2(sx * f, sy * f);
    if (accumulate) {
        const float2 old = vo[id];
        r.x += old.x; r.y += old.y;
    }
    vo[id] = r;
}

__global__ void squash_k(const float* __restrict__ s, float* __restrict__ vout,
                         int accumulate)
{
    const int idx = blockIdx.x * 256 + threadIdx.x;
    const float val = s[idx];
    float sq = val * val;
#pragma unroll
    for (int m = 1; m < 32; m <<= 1) sq += __shfl_xor(sq, m);
    const float f = sq / ((1.0f + sq) * sqrtf(sq + 1e-8f));
    const float v = val * f;
    if (accumulate) vout[idx] += v;
    else            vout[idx] = v;
}

extern "C" void kernel_launch(void* const* d_in, const int* in_sizes, int n_in,
                              void* d_out, int out_size, void* d_ws, size_t ws_size,
                              hipStream_t stream)
{
    (void)in_sizes; (void)n_in; (void)out_size;
    const float* x = (const float*)d_in[0];
    const float* W = (const float*)d_in[1];
    float* out = (float*)d_out;

    const size_t uBytes    = (size_t)B_ * NIN * NOUT * DOUT * 2;           // 256 MiB
    const size_t partBytes = (size_t)NBLK * PART_PER_BLK * sizeof(float2); // 32 MiB
    const size_t vBytes    = (size_t)B_ * NOUT * DOUT * sizeof(float);     // 256 KiB

    if (ws_size >= uBytes + partBytes + vBytes) {
        // ---- main path: u materialized in bf16 (r14 layout) ----
        unsigned* uws  = (unsigned*)d_ws;
        float2*   p1   = (float2*)((char*)d_ws + uBytes);
        float*    p2   = (float*)p1;                       // 32 MiB, reused
        float*    vA   = (float*)((char*)d_ws + uBytes + partBytes);

        caps_pass1u<<<dim3(NBLK), dim3(TPB), 0, stream>>>(W, x, uws, p1);
        reduce_squash<<<dim3(128), dim3(256), 0, stream>>>(p1, vA, 0);     // vA = v1

        caps_pass23u<<<dim3(NBLK2), dim3(TPB2), 0, stream>>>(uws, vA, p2);
        reduce_squash2<<<dim3(256), dim3(256), 0, stream>>>(p2, vA, 1);    // vA = v1+v2

        caps_pass23u<<<dim3(NBLK2), dim3(TPB2), 0, stream>>>(uws, vA, p2);
        reduce_squash2<<<dim3(256), dim3(256), 0, stream>>>(p2, out, 0);   // out = v3
    } else if (ws_size >= partBytes + vBytes) {
        // ---- r8 partial path ----
        float2* part = (float2*)d_ws;
        float*  vA   = (float*)((char*)d_ws + partBytes);

        caps_pass<1, false><<<dim3(NBLK), dim3(TPB), 0, stream>>>(W, x, nullptr, nullptr, part);
        reduce_squash<<<dim3(128), dim3(256), 0, stream>>>(part, vA, 0);

        caps_pass<2, false><<<dim3(NBLK), dim3(TPB), 0, stream>>>(W, x, vA, nullptr, part);
        reduce_squash<<<dim3(128), dim3(256), 0, stream>>>(part, vA, 1);

        caps_pass<2, false><<<dim3(NBLK), dim3(TPB), 0, stream>>>(W, x, vA, nullptr, part);
        reduce_squash<<<dim3(128), dim3(256), 0, stream>>>(part, out, 0);
    } else {
        // ---- atomic fallback ----
        float* s  = (float*)d_ws;
        float* vA = s + B_ * NOUT * DOUT;

        hipMemsetAsync(s, 0, vBytes, stream);
        caps_pass<1, true><<<dim3(NBLK), dim3(TPB), 0, stream>>>(W, x, nullptr, s, nullptr);
        squash_k<<<dim3(256), dim3(256), 0, stream>>>(s, vA, 0);

        hipMemsetAsync(s, 0, vBytes, stream);
        caps_pass<2, true><<<dim3(NBLK), dim3(TPB), 0, stream>>>(W, x, vA, s, nullptr);
        squash_k<<<dim3(256), dim3(256), 0, stream>>>(s, vA, 1);

        hipMemsetAsync(s, 0, vBytes, stream);
        caps_pass<2, true><<<dim3(NBLK), dim3(TPB), 0, stream>>>(W, x, vA, s, nullptr);
        squash_k<<<dim3(256), dim3(256), 0, stream>>>(s, out, 0);
    }
}